// Round 13
// baseline (378.817 us; speedup 1.0000x reference)
//
#include <hip/hip_runtime.h>
#include <math.h>

// ---------------- zero counters: counts | ecounts ----------------
__global__ __launch_bounds__(256) void k_zero(int* __restrict__ p, int n4) {
  int i = blockIdx.x * blockDim.x + threadIdx.x;
  if (i < n4) reinterpret_cast<int4*>(p)[i] = make_int4(0, 0, 0, 0);
}

// ---------------- histogram + position record: points by zone, edges by col ----------------
__global__ __launch_bounds__(256) void k_hist2(const int* __restrict__ zone, int N,
                                               const int* __restrict__ ecol, int E,
                                               int* __restrict__ counts, int* __restrict__ ecounts,
                                               int* __restrict__ pos, int* __restrict__ epos) {
  int i = blockIdx.x * blockDim.x + threadIdx.x;
  if (i < N) {
    pos[i] = atomicAdd(&counts[zone[i]], 1);
  } else if (i < N + E) {
    int e = i - N;
    epos[e] = atomicAdd(&ecounts[ecol[e]], 1);
  }
}

// ---------------- scan (blocks 0,1) + precompute (block 2) ----------------
__global__ __launch_bounds__(256) void k_scan3(
    const int* __restrict__ counts, const int* __restrict__ ecounts,
    int R, int* __restrict__ startb, int* __restrict__ estartb, float* __restrict__ dinv,
    const float* __restrict__ S, const float* __restrict__ Wq, const float* __restrict__ bq,
    const float* __restrict__ Wk, const float* __restrict__ bk,
    float* __restrict__ qvec, float* __restrict__ A, float* __restrict__ cvec) {
  const int t = threadIdx.x;
  if (blockIdx.x == 2) {
    __shared__ float s_S[128];
    __shared__ float s_q[128];
    if (t < 128) s_S[t] = S[t];
    __syncthreads();
    if (t < 128) {
      float acc = bq[t];
      for (int i = 0; i < 128; ++i) acc += s_S[i] * Wq[i * 128 + t];
      qvec[t] = acc;
      s_q[t] = acc;
    }
    __syncthreads();
    if (t < 128) {
      const float scale = 0.088388347648318447f; // 1/sqrt(128)
      for (int h = 0; h < 4; ++h) {
        float a = 0.f;
        for (int d = 0; d < 32; ++d) a += Wk[t * 128 + h * 32 + d] * s_q[h * 32 + d];
        A[t * 4 + h] = a * scale;
      }
      if (t < 4) {
        float cc = 0.f;
        for (int d = 0; d < 32; ++d) cc += bk[t * 32 + d] * s_q[t * 32 + d];
        cvec[t] = cc * scale;
      }
    }
    return;
  }
  __shared__ int part[256];
  const bool edges = (blockIdx.x == 1);
  const int* __restrict__ cnt = edges ? ecounts : counts;
  int* __restrict__ outp = edges ? estartb : startb;
  int chunk = (R + 255) / 256;
  int b = t * chunk, e = min(b + chunk, R);
  int s = 0;
  for (int i = b; i < e; ++i) s += cnt[i];
  part[t] = s;
  __syncthreads();
  for (int off = 1; off < 256; off <<= 1) {
    int v = (t >= off) ? part[t - off] : 0;
    __syncthreads();
    part[t] += v;
    __syncthreads();
  }
  int run = part[t] - s; // exclusive prefix
  for (int i = b; i < e; ++i) {
    outp[i] = run;
    int c = cnt[i];
    run += c;
    if (edges) dinv[i] = rsqrtf((float)(c + 1)); // +1 self loop
  }
  if (t == 255) outp[R] = part[255];
}

// ---------------- atomic-free scatter using recorded positions ----------------
__global__ __launch_bounds__(256) void k_scatter2(
    const int* __restrict__ zone, int N, const int* __restrict__ pos,
    const int* __restrict__ erow, const int* __restrict__ ecol, int E, const int* __restrict__ epos,
    const int* __restrict__ startb, int* __restrict__ perm,
    const int* __restrict__ estartb, int* __restrict__ erow_s) {
  int i = blockIdx.x * blockDim.x + threadIdx.x;
  if (i < N) {
    perm[startb[zone[i]] + pos[i]] = i;
  } else if (i < N + E) {
    int e = i - N;
    erow_s[estartb[ecol[e]] + epos[e]] = erow[e];
  }
}

// ---------------- fused attention pass: ONE region per wave (HW-scheduler balanced churn) --------
// grid = ceil(R/4) blocks x 4 waves. Round-8 loop body (8-row batches, prefetched indices).
// Lane sl owns dims 4*sl..4*sl+3. 6-shuffle head-compaction reduce; 1 exp + 3 distribute shuffles.
// Flush split across halves: half 0 stores heads 0,1; half 1 stores heads 2,3.
__global__ __launch_bounds__(256) void k_fused(
    const float* __restrict__ x, const int* __restrict__ perm, const int* __restrict__ startb,
    const float* __restrict__ Aw, const float* __restrict__ cvec,
    float* __restrict__ Xagg, float* __restrict__ denom, int R) {
  const int tid = threadIdx.x;
  const int lane = tid & 63;
  const int half = lane >> 5;
  const int sl = lane & 31;
  const int d0 = sl * 4;
  const int myh = lane & 3;
  const int r = blockIdx.x * 4 + (tid >> 6);
  if (r >= R) return;

  float a[4][4];
#pragma unroll
  for (int dd = 0; dd < 4; ++dd)
#pragma unroll
    for (int h = 0; h < 4; ++h) a[dd][h] = Aw[(d0 + dd) * 4 + h];
  const float cl = cvec[myh];

  const int s0 = startb[r], s1 = startb[r + 1];
  float xagg[4][4] = {};  // [dim][hrel]
  float dsum[4] = {};     // [hrel]

  int base = s0 + half * 8;
  int idx[8];
#pragma unroll
  for (int k = 0; k < 8; ++k) {
    const int j = base + k;
    idx[k] = (j < s1) ? perm[j] : -1;
  }
  for (; base < s1; base += 16) {
    float4 xv[8];
#pragma unroll
    for (int k = 0; k < 8; ++k) {
      xv[k] = (idx[k] >= 0)
            ? *reinterpret_cast<const float4*>(x + (size_t)idx[k] * 128 + d0)
            : make_float4(0.f, 0.f, 0.f, 0.f);
    }
    int idxn[8];
    const int nb = base + 16;
#pragma unroll
    for (int k = 0; k < 8; ++k) {
      const int j = nb + k;
      idxn[k] = (j < s1) ? perm[j] : -1;
    }
    float red[8];
#pragma unroll
    for (int k = 0; k < 8; ++k) {
      const float4 v = xv[k];
      const float p0 = v.x * a[0][0] + v.y * a[1][0] + v.z * a[2][0] + v.w * a[3][0];
      const float p1 = v.x * a[0][1] + v.y * a[1][1] + v.z * a[2][1] + v.w * a[3][1];
      const float p2 = v.x * a[0][2] + v.y * a[1][2] + v.z * a[2][2] + v.w * a[3][2];
      const float p3 = v.x * a[0][3] + v.y * a[1][3] + v.z * a[2][3] + v.w * a[3][3];
      float a01 = (lane & 1) ? p1 : p0;
      float b01 = (lane & 1) ? p0 : p1;
      a01 += __shfl_xor(b01, 1, 64);
      float a23 = (lane & 1) ? p3 : p2;
      float b23 = (lane & 1) ? p2 : p3;
      a23 += __shfl_xor(b23, 1, 64);
      float aa = (lane & 2) ? a23 : a01;
      float bb = (lane & 2) ? a01 : a23;
      aa += __shfl_xor(bb, 2, 64);
      aa += __shfl_xor(aa, 4, 64);
      aa += __shfl_xor(aa, 8, 64);
      aa += __shfl_xor(aa, 16, 64);
      red[k] = aa;
    }
#pragma unroll
    for (int k = 0; k < 8; ++k) {
      const float e0 = (idx[k] >= 0) ? __expf(red[k] + cl) : 0.f; // head myh
      const float e1 = __shfl_xor(e0, 1, 64);                     // head myh^1
      const float e2 = __shfl_xor(e0, 2, 64);                     // head myh^2
      const float e3 = __shfl_xor(e0, 3, 64);                     // head myh^3
      dsum[0] += e0; dsum[1] += e1; dsum[2] += e2; dsum[3] += e3;
      const float4 v = xv[k];
      xagg[0][0] += e0 * v.x; xagg[0][1] += e1 * v.x; xagg[0][2] += e2 * v.x; xagg[0][3] += e3 * v.x;
      xagg[1][0] += e0 * v.y; xagg[1][1] += e1 * v.y; xagg[1][2] += e2 * v.y; xagg[1][3] += e3 * v.y;
      xagg[2][0] += e0 * v.z; xagg[2][1] += e1 * v.z; xagg[2][2] += e2 * v.z; xagg[2][3] += e3 * v.z;
      xagg[3][0] += e0 * v.w; xagg[3][1] += e1 * v.w; xagg[3][2] += e2 * v.w; xagg[3][3] += e3 * v.w;
    }
#pragma unroll
    for (int k = 0; k < 8; ++k) idx[k] = idxn[k];
  }

  // combine the two half-waves (lane l and l^32 share myh -> same hrel semantics)
#pragma unroll
  for (int dd = 0; dd < 4; ++dd)
#pragma unroll
    for (int h = 0; h < 4; ++h) xagg[dd][h] += __shfl_xor(xagg[dd][h], 32, 64);
#pragma unroll
  for (int h = 0; h < 4; ++h) dsum[h] += __shfl_xor(dsum[h], 32, 64);

  // relative -> absolute heads: abs[h] = rel[h ^ myh], static-indexed selects
  {
    const bool m1 = (myh & 1) != 0;
    const bool m2 = (myh & 2) != 0;
    float outv[4][4]; // [abs head][dim]
#pragma unroll
    for (int dd = 0; dd < 4; ++dd) {
      const float b0 = m1 ? xagg[dd][1] : xagg[dd][0];
      const float b1 = m1 ? xagg[dd][0] : xagg[dd][1];
      const float b2 = m1 ? xagg[dd][3] : xagg[dd][2];
      const float b3 = m1 ? xagg[dd][2] : xagg[dd][3];
      outv[0][dd] = m2 ? b2 : b0;
      outv[1][dd] = m2 ? b3 : b1;
      outv[2][dd] = m2 ? b0 : b2;
      outv[3][dd] = m2 ? b1 : b3;
    }
    const int h0 = half * 2; // half 0 -> heads 0,1; half 1 -> heads 2,3
#pragma unroll
    for (int hh = 0; hh < 2; ++hh) {
      const int h = h0 + hh;
      const float4 v = make_float4(outv[h][0], outv[h][1], outv[h][2], outv[h][3]);
      *reinterpret_cast<float4*>(Xagg + (size_t)r * 512 + h * 128 + d0) = v;
    }
    if (lane == 0) { // myh==0 -> dsum already absolute
      *reinterpret_cast<float4*>(denom + (size_t)r * 4) =
          make_float4(dsum[0], dsum[1], dsum[2], dsum[3]);
    }
  }
}

// ---------------- batched epilogue: attn -> O -> O+relu(O@Wo+bo) -> h = O2@Wg  (8 regions/block) --------
__global__ __launch_bounds__(256) void k_epilogue(
    const float* __restrict__ Xagg, const float* __restrict__ denom, const float* __restrict__ qvec,
    const float* __restrict__ Wv, const float* __restrict__ bv,
    const float* __restrict__ Wo, const float* __restrict__ bo,
    const float* __restrict__ Wg, float* __restrict__ hout, int R) {
  const int r0 = blockIdx.x * 8;
  const int tid = threadIdx.x;
  __shared__ float s_xa[8 * 512];
  __shared__ float s_den[8 * 4];
  __shared__ float s_O[8 * 128];
  __shared__ float s_O2[8 * 128];

  for (int t = tid; t < 8 * 512; t += 256) {
    int rl = t >> 9;
    s_xa[t] = (r0 + rl < R) ? Xagg[(size_t)r0 * 512 + t] : 0.f;
  }
  if (tid < 32) {
    int rl = tid >> 2;
    s_den[tid] = (r0 + rl < R) ? denom[r0 * 4 + tid] : 1.f;
  }
  __syncthreads();

  for (int o = tid; o < 1024; o += 256) {
    int rl = o >> 7, t = o & 127, h = t >> 5;
    float acc = 0.f;
    const float* xa = &s_xa[rl * 512 + h * 128];
    for (int j = 0; j < 128; j += 4) {
      float4 x4 = *reinterpret_cast<const float4*>(xa + j);
      acc += x4.x * Wv[j * 128 + t] + x4.y * Wv[(j + 1) * 128 + t]
           + x4.z * Wv[(j + 2) * 128 + t] + x4.w * Wv[(j + 3) * 128 + t];
    }
    float dn = s_den[rl * 4 + h];
    float attn = (acc + dn * bv[t]) / fmaxf(dn, 1e-9f);
    s_O[o] = qvec[t] + attn;
  }
  __syncthreads();

  for (int o = tid; o < 1024; o += 256) {
    int rl = o >> 7, t = o & 127;
    float acc = bo[t];
    const float* ov = &s_O[rl * 128];
    for (int j = 0; j < 128; j += 4) {
      float4 x4 = *reinterpret_cast<const float4*>(ov + j);
      acc += x4.x * Wo[j * 128 + t] + x4.y * Wo[(j + 1) * 128 + t]
           + x4.z * Wo[(j + 2) * 128 + t] + x4.w * Wo[(j + 3) * 128 + t];
    }
    s_O2[o] = s_O[o] + fmaxf(acc, 0.f);
  }
  __syncthreads();

  for (int o = tid; o < 1024; o += 256) {
    int rl = o >> 7, t = o & 127;
    float acc = 0.f;
    const float* ov = &s_O2[rl * 128];
    for (int j = 0; j < 128; j += 4) {
      float4 x4 = *reinterpret_cast<const float4*>(ov + j);
      acc += x4.x * Wg[j * 128 + t] + x4.y * Wg[(j + 1) * 128 + t]
           + x4.z * Wg[(j + 2) * 128 + t] + x4.w * Wg[(j + 3) * 128 + t];
    }
    if (r0 + rl < R) hout[(size_t)(r0 + rl) * 128 + t] = acc;
  }
}

// ---------------- fused GCN: self-loop + CSR edge gather + bias + PReLU (wave per region) ----------------
__global__ __launch_bounds__(256) void k_gcn(
    const int* __restrict__ estartb, const int* __restrict__ erow_s,
    const float* __restrict__ dinv, const float* __restrict__ hbuf,
    const float* __restrict__ bg, const float* __restrict__ pw,
    float* __restrict__ out, int R) {
  const int r = blockIdx.x * 4 + (threadIdx.x >> 6);
  if (r >= R) return;
  const int lane = threadIdx.x & 63;
  const int d0 = lane * 2;
  const float dr = dinv[r];
  const float2 hc = *reinterpret_cast<const float2*>(hbuf + (size_t)r * 128 + d0);
  float accx = dr * dr * hc.x;
  float accy = dr * dr * hc.y;
  const int e0 = estartb[r], e1 = estartb[r + 1];
  for (int e = e0; e < e1; ++e) {
    const int rr = erow_s[e];
    const float w = dinv[rr] * dr;
    const float2 hv = *reinterpret_cast<const float2*>(hbuf + (size_t)rr * 128 + d0);
    accx += w * hv.x;
    accy += w * hv.y;
  }
  const float2 b = *reinterpret_cast<const float2*>(bg + d0);
  const float2 pv = *reinterpret_cast<const float2*>(pw + d0);
  const float t0 = accx + b.x;
  const float t1 = accy + b.y;
  out[(size_t)r * 128 + d0]     = (t0 >= 0.f) ? t0 : pv.x * t0;
  out[(size_t)r * 128 + d0 + 1] = (t1 >= 0.f) ? t1 : pv.y * t1;
}

// ---------------- host ----------------
extern "C" void kernel_launch(void* const* d_in, const int* in_sizes, int n_in,
                              void* d_out, int out_size, void* d_ws, size_t ws_size,
                              hipStream_t stream) {
  const float* x   = (const float*)d_in[0];
  const int*   zone = (const int*)d_in[1];
  const int*   eidx = (const int*)d_in[2];
  const float* S   = (const float*)d_in[4];
  const float* Wq  = (const float*)d_in[5];
  const float* bq  = (const float*)d_in[6];
  const float* Wk  = (const float*)d_in[7];
  const float* bk  = (const float*)d_in[8];
  const float* Wv  = (const float*)d_in[9];
  const float* bv  = (const float*)d_in[10];
  const float* Wo  = (const float*)d_in[11];
  const float* bo  = (const float*)d_in[12];
  const float* Wg  = (const float*)d_in[13];
  const float* bg  = (const float*)d_in[14];
  const float* pw  = (const float*)d_in[15];
  float* out = (float*)d_out;

  const int N = in_sizes[0] / 128;
  const int E = in_sizes[2] / 2;
  const int R = out_size / 128;
  const int* erow = eidx;
  const int* ecol = eidx + E;

  char* wsb = (char*)d_ws;
  size_t off = 0;
  auto alloc = [&](size_t bytes) -> void* {
    void* p = wsb + off;
    off = (off + bytes + 255) & ~(size_t)255;
    return p;
  };
  // zeroed int block: counts | ecounts
  int* izero  = (int*)alloc((size_t)2 * R * 4 + 16);
  int* counts = izero;
  int* ecounts= izero + R;

  float* qvec  = (float*)alloc(128 * 4);
  float* A     = (float*)alloc(512 * 4);
  float* cvec  = (float*)alloc(4 * 4);
  int*   startb = (int*)alloc((size_t)(R + 1) * 4);
  int*   estartb= (int*)alloc((size_t)(R + 1) * 4);
  float* dinv  = (float*)alloc((size_t)R * 4);
  int*   erow_s= (int*)alloc((size_t)E * 4);
  int*   epos  = (int*)alloc((size_t)E * 4);
  int*   perm  = (int*)alloc((size_t)N * 4);
  int*   pos   = (int*)alloc((size_t)N * 4);
  float* Xagg  = (float*)alloc((size_t)R * 512 * 4);
  float* denom = (float*)alloc((size_t)R * 4 * 4);
  float* hbuf  = (float*)alloc((size_t)R * 128 * 4);

  const int n4 = (2 * R + 3) / 4;
  k_zero<<<(n4 + 255) / 256, 256, 0, stream>>>(izero, n4);
  k_hist2<<<(N + E + 255) / 256, 256, 0, stream>>>(zone, N, ecol, E, counts, ecounts, pos, epos);
  k_scan3<<<3, 256, 0, stream>>>(counts, ecounts, R, startb, estartb, dinv,
                                 S, Wq, bq, Wk, bk, qvec, A, cvec);
  k_scatter2<<<(N + E + 255) / 256, 256, 0, stream>>>(zone, N, pos, erow, ecol, E, epos,
                                                      startb, perm, estartb, erow_s);
  k_fused<<<(R + 3) / 4, 256, 0, stream>>>(x, perm, startb, A, cvec, Xagg, denom, R);
  k_epilogue<<<(R + 7) / 8, 256, 0, stream>>>(Xagg, denom, qvec, Wv, bv, Wo, bo, Wg, hbuf, R);
  k_gcn<<<(R + 3) / 4, 256, 0, stream>>>(estartb, erow_s, dinv, hbuf, bg, pw, out, R);
}

// Round 14
// 321.334 us; speedup vs baseline: 1.1789x; 1.1789x over previous
//
#include <hip/hip_runtime.h>
#include <math.h>

// ---------------- zero counters: counts | ecounts ----------------
__global__ __launch_bounds__(256) void k_zero(int* __restrict__ p, int n4) {
  int i = blockIdx.x * blockDim.x + threadIdx.x;
  if (i < n4) reinterpret_cast<int4*>(p)[i] = make_int4(0, 0, 0, 0);
}

// ---------------- histogram + position record: points by zone, edges by col ----------------
__global__ __launch_bounds__(256) void k_hist2(const int* __restrict__ zone, int N,
                                               const int* __restrict__ ecol, int E,
                                               int* __restrict__ counts, int* __restrict__ ecounts,
                                               int* __restrict__ pos, int* __restrict__ epos) {
  int i = blockIdx.x * blockDim.x + threadIdx.x;
  if (i < N) {
    pos[i] = atomicAdd(&counts[zone[i]], 1);
  } else if (i < N + E) {
    int e = i - N;
    epos[e] = atomicAdd(&ecounts[ecol[e]], 1);
  }
}

// ---------------- scan (blocks 0,1) + precompute (block 2) ----------------
__global__ __launch_bounds__(256) void k_scan3(
    const int* __restrict__ counts, const int* __restrict__ ecounts,
    int R, int* __restrict__ startb, int* __restrict__ estartb, float* __restrict__ dinv,
    const float* __restrict__ S, const float* __restrict__ Wq, const float* __restrict__ bq,
    const float* __restrict__ Wk, const float* __restrict__ bk,
    float* __restrict__ qvec, float* __restrict__ A, float* __restrict__ cvec) {
  const int t = threadIdx.x;
  if (blockIdx.x == 2) {
    __shared__ float s_S[128];
    __shared__ float s_q[128];
    if (t < 128) s_S[t] = S[t];
    __syncthreads();
    if (t < 128) {
      float acc = bq[t];
      for (int i = 0; i < 128; ++i) acc += s_S[i] * Wq[i * 128 + t];
      qvec[t] = acc;
      s_q[t] = acc;
    }
    __syncthreads();
    if (t < 128) {
      const float scale = 0.088388347648318447f; // 1/sqrt(128)
      for (int h = 0; h < 4; ++h) {
        float a = 0.f;
        for (int d = 0; d < 32; ++d) a += Wk[t * 128 + h * 32 + d] * s_q[h * 32 + d];
        A[t * 4 + h] = a * scale;
      }
      if (t < 4) {
        float cc = 0.f;
        for (int d = 0; d < 32; ++d) cc += bk[t * 32 + d] * s_q[t * 32 + d];
        cvec[t] = cc * scale;
      }
    }
    return;
  }
  __shared__ int part[256];
  const bool edges = (blockIdx.x == 1);
  const int* __restrict__ cnt = edges ? ecounts : counts;
  int* __restrict__ outp = edges ? estartb : startb;
  int chunk = (R + 255) / 256;
  int b = t * chunk, e = min(b + chunk, R);
  int s = 0;
  for (int i = b; i < e; ++i) s += cnt[i];
  part[t] = s;
  __syncthreads();
  for (int off = 1; off < 256; off <<= 1) {
    int v = (t >= off) ? part[t - off] : 0;
    __syncthreads();
    part[t] += v;
    __syncthreads();
  }
  int run = part[t] - s; // exclusive prefix
  for (int i = b; i < e; ++i) {
    outp[i] = run;
    int c = cnt[i];
    run += c;
    if (edges) dinv[i] = rsqrtf((float)(c + 1)); // +1 self loop
  }
  if (t == 255) outp[R] = part[255];
}

// ---------------- atomic-free scatter using recorded positions ----------------
__global__ __launch_bounds__(256) void k_scatter2(
    const int* __restrict__ zone, int N, const int* __restrict__ pos,
    const int* __restrict__ erow, const int* __restrict__ ecol, int E, const int* __restrict__ epos,
    const int* __restrict__ startb, int* __restrict__ perm,
    const int* __restrict__ estartb, int* __restrict__ erow_s) {
  int i = blockIdx.x * blockDim.x + threadIdx.x;
  if (i < N) {
    perm[startb[zone[i]] + pos[i]] = i;
  } else if (i < N + E) {
    int e = i - N;
    erow_s[estartb[ecol[e]] + epos[e]] = erow[e];
  }
}

// ---------------- fused attention pass: wave per region (grid-stride), 12-pt batches/half-wave --------
// Round-12 structure (proven 314.5 us) with batch widened 8->12 for +50% in-flight rows.
// Lane sl owns dims 4*sl..4*sl+3. 6-shuffle head-compaction reduce leaves lane with the
// score for head (lane&3); 1 exp + 3 distribute shuffles. Accumulators head-RELATIVE.
__global__ __launch_bounds__(256) void k_fused(
    const float* __restrict__ x, const int* __restrict__ perm, const int* __restrict__ startb,
    const float* __restrict__ Aw, const float* __restrict__ cvec,
    float* __restrict__ Xagg, float* __restrict__ denom, int R) {
  const int tid = threadIdx.x;
  const int lane = tid & 63;
  const int half = lane >> 5;
  const int sl = lane & 31;
  const int d0 = sl * 4;
  const int myh = lane & 3;
  const int gw = blockIdx.x * 4 + (tid >> 6);
  const int nw = gridDim.x * 4;

  float a[4][4];
#pragma unroll
  for (int dd = 0; dd < 4; ++dd)
#pragma unroll
    for (int h = 0; h < 4; ++h) a[dd][h] = Aw[(d0 + dd) * 4 + h];
  const float cl = cvec[myh];

  for (int r = gw; r < R; r += nw) {
    const int s0 = startb[r], s1 = startb[r + 1];
    float xagg[4][4] = {};  // [dim][hrel]
    float dsum[4] = {};     // [hrel]

    int base = s0 + half * 12;
    int idx[12];
#pragma unroll
    for (int k = 0; k < 12; ++k) {
      const int j = base + k;
      idx[k] = (j < s1) ? perm[j] : -1;
    }
    for (; base < s1; base += 24) {
      float4 xv[12];
#pragma unroll
      for (int k = 0; k < 12; ++k) {
        xv[k] = (idx[k] >= 0)
              ? *reinterpret_cast<const float4*>(x + (size_t)idx[k] * 128 + d0)
              : make_float4(0.f, 0.f, 0.f, 0.f);
      }
      int idxn[12];
      const int nb = base + 24;
#pragma unroll
      for (int k = 0; k < 12; ++k) {
        const int j = nb + k;
        idxn[k] = (j < s1) ? perm[j] : -1;
      }
      float red[12];
#pragma unroll
      for (int k = 0; k < 12; ++k) {
        const float4 v = xv[k];
        const float p0 = v.x * a[0][0] + v.y * a[1][0] + v.z * a[2][0] + v.w * a[3][0];
        const float p1 = v.x * a[0][1] + v.y * a[1][1] + v.z * a[2][1] + v.w * a[3][1];
        const float p2 = v.x * a[0][2] + v.y * a[1][2] + v.z * a[2][2] + v.w * a[3][2];
        const float p3 = v.x * a[0][3] + v.y * a[1][3] + v.z * a[2][3] + v.w * a[3][3];
        float a01 = (lane & 1) ? p1 : p0;
        float b01 = (lane & 1) ? p0 : p1;
        a01 += __shfl_xor(b01, 1, 64);
        float a23 = (lane & 1) ? p3 : p2;
        float b23 = (lane & 1) ? p2 : p3;
        a23 += __shfl_xor(b23, 1, 64);
        float aa = (lane & 2) ? a23 : a01;
        float bb = (lane & 2) ? a01 : a23;
        aa += __shfl_xor(bb, 2, 64);
        aa += __shfl_xor(aa, 4, 64);
        aa += __shfl_xor(aa, 8, 64);
        aa += __shfl_xor(aa, 16, 64);
        red[k] = aa;
      }
#pragma unroll
      for (int k = 0; k < 12; ++k) {
        const float e0 = (idx[k] >= 0) ? __expf(red[k] + cl) : 0.f; // head myh
        const float e1 = __shfl_xor(e0, 1, 64);                     // head myh^1
        const float e2 = __shfl_xor(e0, 2, 64);                     // head myh^2
        const float e3 = __shfl_xor(e0, 3, 64);                     // head myh^3
        dsum[0] += e0; dsum[1] += e1; dsum[2] += e2; dsum[3] += e3;
        const float4 v = xv[k];
        xagg[0][0] += e0 * v.x; xagg[0][1] += e1 * v.x; xagg[0][2] += e2 * v.x; xagg[0][3] += e3 * v.x;
        xagg[1][0] += e0 * v.y; xagg[1][1] += e1 * v.y; xagg[1][2] += e2 * v.y; xagg[1][3] += e3 * v.y;
        xagg[2][0] += e0 * v.z; xagg[2][1] += e1 * v.z; xagg[2][2] += e2 * v.z; xagg[2][3] += e3 * v.z;
        xagg[3][0] += e0 * v.w; xagg[3][1] += e1 * v.w; xagg[3][2] += e2 * v.w; xagg[3][3] += e3 * v.w;
      }
#pragma unroll
      for (int k = 0; k < 12; ++k) idx[k] = idxn[k];
    }

#pragma unroll
    for (int dd = 0; dd < 4; ++dd)
#pragma unroll
      for (int h = 0; h < 4; ++h) xagg[dd][h] += __shfl_xor(xagg[dd][h], 32, 64);
#pragma unroll
    for (int h = 0; h < 4; ++h) dsum[h] += __shfl_xor(dsum[h], 32, 64);

    if (half == 0) {
      const bool m1 = (myh & 1) != 0;
      const bool m2 = (myh & 2) != 0;
      float outv[4][4]; // [abs head][dim]
#pragma unroll
      for (int dd = 0; dd < 4; ++dd) {
        const float b0 = m1 ? xagg[dd][1] : xagg[dd][0];
        const float b1 = m1 ? xagg[dd][0] : xagg[dd][1];
        const float b2 = m1 ? xagg[dd][3] : xagg[dd][2];
        const float b3 = m1 ? xagg[dd][2] : xagg[dd][3];
        outv[0][dd] = m2 ? b2 : b0;
        outv[1][dd] = m2 ? b3 : b1;
        outv[2][dd] = m2 ? b0 : b2;
        outv[3][dd] = m2 ? b1 : b3;
      }
#pragma unroll
      for (int h = 0; h < 4; ++h) {
        const float4 v = make_float4(outv[h][0], outv[h][1], outv[h][2], outv[h][3]);
        *reinterpret_cast<float4*>(Xagg + (size_t)r * 512 + h * 128 + d0) = v;
      }
      if (sl == 0) {
        *reinterpret_cast<float4*>(denom + (size_t)r * 4) =
            make_float4(dsum[0], dsum[1], dsum[2], dsum[3]);
      }
    }
  }
}

// ---------------- batched epilogue: attn -> O -> O+relu(O@Wo+bo) -> h = O2@Wg  (8 regions/block) --------
__global__ __launch_bounds__(256) void k_epilogue(
    const float* __restrict__ Xagg, const float* __restrict__ denom, const float* __restrict__ qvec,
    const float* __restrict__ Wv, const float* __restrict__ bv,
    const float* __restrict__ Wo, const float* __restrict__ bo,
    const float* __restrict__ Wg, float* __restrict__ hout, int R) {
  const int r0 = blockIdx.x * 8;
  const int tid = threadIdx.x;
  __shared__ float s_xa[8 * 512];
  __shared__ float s_den[8 * 4];
  __shared__ float s_O[8 * 128];
  __shared__ float s_O2[8 * 128];

  for (int t = tid; t < 8 * 512; t += 256) {
    int rl = t >> 9;
    s_xa[t] = (r0 + rl < R) ? Xagg[(size_t)r0 * 512 + t] : 0.f;
  }
  if (tid < 32) {
    int rl = tid >> 2;
    s_den[tid] = (r0 + rl < R) ? denom[r0 * 4 + tid] : 1.f;
  }
  __syncthreads();

  for (int o = tid; o < 1024; o += 256) {
    int rl = o >> 7, t = o & 127, h = t >> 5;
    float acc = 0.f;
    const float* xa = &s_xa[rl * 512 + h * 128];
    for (int j = 0; j < 128; j += 4) {
      float4 x4 = *reinterpret_cast<const float4*>(xa + j);
      acc += x4.x * Wv[j * 128 + t] + x4.y * Wv[(j + 1) * 128 + t]
           + x4.z * Wv[(j + 2) * 128 + t] + x4.w * Wv[(j + 3) * 128 + t];
    }
    float dn = s_den[rl * 4 + h];
    float attn = (acc + dn * bv[t]) / fmaxf(dn, 1e-9f);
    s_O[o] = qvec[t] + attn;
  }
  __syncthreads();

  for (int o = tid; o < 1024; o += 256) {
    int rl = o >> 7, t = o & 127;
    float acc = bo[t];
    const float* ov = &s_O[rl * 128];
    for (int j = 0; j < 128; j += 4) {
      float4 x4 = *reinterpret_cast<const float4*>(ov + j);
      acc += x4.x * Wo[j * 128 + t] + x4.y * Wo[(j + 1) * 128 + t]
           + x4.z * Wo[(j + 2) * 128 + t] + x4.w * Wo[(j + 3) * 128 + t];
    }
    s_O2[o] = s_O[o] + fmaxf(acc, 0.f);
  }
  __syncthreads();

  for (int o = tid; o < 1024; o += 256) {
    int rl = o >> 7, t = o & 127;
    float acc = 0.f;
    const float* ov = &s_O2[rl * 128];
    for (int j = 0; j < 128; j += 4) {
      float4 x4 = *reinterpret_cast<const float4*>(ov + j);
      acc += x4.x * Wg[j * 128 + t] + x4.y * Wg[(j + 1) * 128 + t]
           + x4.z * Wg[(j + 2) * 128 + t] + x4.w * Wg[(j + 3) * 128 + t];
    }
    if (r0 + rl < R) hout[(size_t)(r0 + rl) * 128 + t] = acc;
  }
}

// ---------------- fused GCN: self-loop + CSR edge gather + bias + PReLU (wave per region) ----------------
__global__ __launch_bounds__(256) void k_gcn(
    const int* __restrict__ estartb, const int* __restrict__ erow_s,
    const float* __restrict__ dinv, const float* __restrict__ hbuf,
    const float* __restrict__ bg, const float* __restrict__ pw,
    float* __restrict__ out, int R) {
  const int r = blockIdx.x * 4 + (threadIdx.x >> 6);
  if (r >= R) return;
  const int lane = threadIdx.x & 63;
  const int d0 = lane * 2;
  const float dr = dinv[r];
  const float2 hc = *reinterpret_cast<const float2*>(hbuf + (size_t)r * 128 + d0);
  float accx = dr * dr * hc.x;
  float accy = dr * dr * hc.y;
  const int e0 = estartb[r], e1 = estartb[r + 1];
  for (int e = e0; e < e1; ++e) {
    const int rr = erow_s[e];
    const float w = dinv[rr] * dr;
    const float2 hv = *reinterpret_cast<const float2*>(hbuf + (size_t)rr * 128 + d0);
    accx += w * hv.x;
    accy += w * hv.y;
  }
  const float2 b = *reinterpret_cast<const float2*>(bg + d0);
  const float2 pv = *reinterpret_cast<const float2*>(pw + d0);
  const float t0 = accx + b.x;
  const float t1 = accy + b.y;
  out[(size_t)r * 128 + d0]     = (t0 >= 0.f) ? t0 : pv.x * t0;
  out[(size_t)r * 128 + d0 + 1] = (t1 >= 0.f) ? t1 : pv.y * t1;
}

// ---------------- host ----------------
extern "C" void kernel_launch(void* const* d_in, const int* in_sizes, int n_in,
                              void* d_out, int out_size, void* d_ws, size_t ws_size,
                              hipStream_t stream) {
  const float* x   = (const float*)d_in[0];
  const int*   zone = (const int*)d_in[1];
  const int*   eidx = (const int*)d_in[2];
  const float* S   = (const float*)d_in[4];
  const float* Wq  = (const float*)d_in[5];
  const float* bq  = (const float*)d_in[6];
  const float* Wk  = (const float*)d_in[7];
  const float* bk  = (const float*)d_in[8];
  const float* Wv  = (const float*)d_in[9];
  const float* bv  = (const float*)d_in[10];
  const float* Wo  = (const float*)d_in[11];
  const float* bo  = (const float*)d_in[12];
  const float* Wg  = (const float*)d_in[13];
  const float* bg  = (const float*)d_in[14];
  const float* pw  = (const float*)d_in[15];
  float* out = (float*)d_out;

  const int N = in_sizes[0] / 128;
  const int E = in_sizes[2] / 2;
  const int R = out_size / 128;
  const int* erow = eidx;
  const int* ecol = eidx + E;

  char* wsb = (char*)d_ws;
  size_t off = 0;
  auto alloc = [&](size_t bytes) -> void* {
    void* p = wsb + off;
    off = (off + bytes + 255) & ~(size_t)255;
    return p;
  };
  // zeroed int block: counts | ecounts
  int* izero  = (int*)alloc((size_t)2 * R * 4 + 16);
  int* counts = izero;
  int* ecounts= izero + R;

  float* qvec  = (float*)alloc(128 * 4);
  float* A     = (float*)alloc(512 * 4);
  float* cvec  = (float*)alloc(4 * 4);
  int*   startb = (int*)alloc((size_t)(R + 1) * 4);
  int*   estartb= (int*)alloc((size_t)(R + 1) * 4);
  float* dinv  = (float*)alloc((size_t)R * 4);
  int*   erow_s= (int*)alloc((size_t)E * 4);
  int*   epos  = (int*)alloc((size_t)E * 4);
  int*   perm  = (int*)alloc((size_t)N * 4);
  int*   pos   = (int*)alloc((size_t)N * 4);
  float* Xagg  = (float*)alloc((size_t)R * 512 * 4);
  float* denom = (float*)alloc((size_t)R * 4 * 4);
  float* hbuf  = (float*)alloc((size_t)R * 128 * 4);

  const int n4 = (2 * R + 3) / 4;
  k_zero<<<(n4 + 255) / 256, 256, 0, stream>>>(izero, n4);
  k_hist2<<<(N + E + 255) / 256, 256, 0, stream>>>(zone, N, ecol, E, counts, ecounts, pos, epos);
  k_scan3<<<3, 256, 0, stream>>>(counts, ecounts, R, startb, estartb, dinv,
                                 S, Wq, bq, Wk, bk, qvec, A, cvec);
  k_scatter2<<<(N + E + 255) / 256, 256, 0, stream>>>(zone, N, pos, erow, ecol, E, epos,
                                                      startb, perm, estartb, erow_s);
  k_fused<<<1024, 256, 0, stream>>>(x, perm, startb, A, cvec, Xagg, denom, R);
  k_epilogue<<<(R + 7) / 8, 256, 0, stream>>>(Xagg, denom, qvec, Wv, bv, Wo, bo, Wg, hbuf, R);
  k_gcn<<<(R + 3) / 4, 256, 0, stream>>>(estartb, erow_s, dinv, hbuf, bg, pw, out, R);
}

// Round 15
// 314.317 us; speedup vs baseline: 1.2052x; 1.0223x over previous
//
#include <hip/hip_runtime.h>
#include <math.h>

// ---------------- zero counters: counts | ecounts ----------------
__global__ __launch_bounds__(256) void k_zero(int* __restrict__ p, int n4) {
  int i = blockIdx.x * blockDim.x + threadIdx.x;
  if (i < n4) reinterpret_cast<int4*>(p)[i] = make_int4(0, 0, 0, 0);
}

// ---------------- histogram + position record: points by zone, edges by col ----------------
__global__ __launch_bounds__(256) void k_hist2(const int* __restrict__ zone, int N,
                                               const int* __restrict__ ecol, int E,
                                               int* __restrict__ counts, int* __restrict__ ecounts,
                                               int* __restrict__ pos, int* __restrict__ epos) {
  int i = blockIdx.x * blockDim.x + threadIdx.x;
  if (i < N) {
    pos[i] = atomicAdd(&counts[zone[i]], 1);
  } else if (i < N + E) {
    int e = i - N;
    epos[e] = atomicAdd(&ecounts[ecol[e]], 1);
  }
}

// ---------------- scan (blocks 0,1) + precompute (block 2) ----------------
__global__ __launch_bounds__(256) void k_scan3(
    const int* __restrict__ counts, const int* __restrict__ ecounts,
    int R, int* __restrict__ startb, int* __restrict__ estartb, float* __restrict__ dinv,
    const float* __restrict__ S, const float* __restrict__ Wq, const float* __restrict__ bq,
    const float* __restrict__ Wk, const float* __restrict__ bk,
    float* __restrict__ qvec, float* __restrict__ A, float* __restrict__ cvec) {
  const int t = threadIdx.x;
  if (blockIdx.x == 2) {
    __shared__ float s_S[128];
    __shared__ float s_q[128];
    if (t < 128) s_S[t] = S[t];
    __syncthreads();
    if (t < 128) {
      float acc = bq[t];
      for (int i = 0; i < 128; ++i) acc += s_S[i] * Wq[i * 128 + t];
      qvec[t] = acc;
      s_q[t] = acc;
    }
    __syncthreads();
    if (t < 128) {
      const float scale = 0.088388347648318447f; // 1/sqrt(128)
      for (int h = 0; h < 4; ++h) {
        float a = 0.f;
        for (int d = 0; d < 32; ++d) a += Wk[t * 128 + h * 32 + d] * s_q[h * 32 + d];
        A[t * 4 + h] = a * scale;
      }
      if (t < 4) {
        float cc = 0.f;
        for (int d = 0; d < 32; ++d) cc += bk[t * 32 + d] * s_q[t * 32 + d];
        cvec[t] = cc * scale;
      }
    }
    return;
  }
  __shared__ int part[256];
  const bool edges = (blockIdx.x == 1);
  const int* __restrict__ cnt = edges ? ecounts : counts;
  int* __restrict__ outp = edges ? estartb : startb;
  int chunk = (R + 255) / 256;
  int b = t * chunk, e = min(b + chunk, R);
  int s = 0;
  for (int i = b; i < e; ++i) s += cnt[i];
  part[t] = s;
  __syncthreads();
  for (int off = 1; off < 256; off <<= 1) {
    int v = (t >= off) ? part[t - off] : 0;
    __syncthreads();
    part[t] += v;
    __syncthreads();
  }
  int run = part[t] - s; // exclusive prefix
  for (int i = b; i < e; ++i) {
    outp[i] = run;
    int c = cnt[i];
    run += c;
    if (edges) dinv[i] = rsqrtf((float)(c + 1)); // +1 self loop
  }
  if (t == 255) outp[R] = part[255];
}

// ---------------- atomic-free scatter using recorded positions ----------------
__global__ __launch_bounds__(256) void k_scatter2(
    const int* __restrict__ zone, int N, const int* __restrict__ pos,
    const int* __restrict__ erow, const int* __restrict__ ecol, int E, const int* __restrict__ epos,
    const int* __restrict__ startb, int* __restrict__ perm,
    const int* __restrict__ estartb, int* __restrict__ erow_s) {
  int i = blockIdx.x * blockDim.x + threadIdx.x;
  if (i < N) {
    perm[startb[zone[i]] + pos[i]] = i;
  } else if (i < N + E) {
    int e = i - N;
    erow_s[estartb[ecol[e]] + epos[e]] = erow[e];
  }
}

// ---------------- fused attention pass: wave per region (grid-stride), 8-pt batches/half-wave --------
// Proven best config (round 12, 314.5 us). Lane sl owns dims 4*sl..4*sl+3.
// 6-shuffle head-compaction reduce leaves lane with the score for head (lane&3);
// 1 exp + 3 distribute shuffles. Accumulators head-RELATIVE: xagg[dd][hrel] = head (myh^hrel).
__global__ __launch_bounds__(256) void k_fused(
    const float* __restrict__ x, const int* __restrict__ perm, const int* __restrict__ startb,
    const float* __restrict__ Aw, const float* __restrict__ cvec,
    float* __restrict__ Xagg, float* __restrict__ denom, int R) {
  const int tid = threadIdx.x;
  const int lane = tid & 63;
  const int half = lane >> 5;
  const int sl = lane & 31;
  const int d0 = sl * 4;
  const int myh = lane & 3;
  const int gw = blockIdx.x * 4 + (tid >> 6);
  const int nw = gridDim.x * 4;

  float a[4][4];
#pragma unroll
  for (int dd = 0; dd < 4; ++dd)
#pragma unroll
    for (int h = 0; h < 4; ++h) a[dd][h] = Aw[(d0 + dd) * 4 + h];
  const float cl = cvec[myh];

  for (int r = gw; r < R; r += nw) {
    const int s0 = startb[r], s1 = startb[r + 1];
    float xagg[4][4] = {};  // [dim][hrel]
    float dsum[4] = {};     // [hrel]

    int base = s0 + half * 8;
    int idx[8];
#pragma unroll
    for (int k = 0; k < 8; ++k) {
      const int j = base + k;
      idx[k] = (j < s1) ? perm[j] : -1;
    }
    for (; base < s1; base += 16) {
      float4 xv[8];
#pragma unroll
      for (int k = 0; k < 8; ++k) {
        xv[k] = (idx[k] >= 0)
              ? *reinterpret_cast<const float4*>(x + (size_t)idx[k] * 128 + d0)
              : make_float4(0.f, 0.f, 0.f, 0.f);
      }
      int idxn[8];
      const int nb = base + 16;
#pragma unroll
      for (int k = 0; k < 8; ++k) {
        const int j = nb + k;
        idxn[k] = (j < s1) ? perm[j] : -1;
      }
      float red[8];
#pragma unroll
      for (int k = 0; k < 8; ++k) {
        const float4 v = xv[k];
        const float p0 = v.x * a[0][0] + v.y * a[1][0] + v.z * a[2][0] + v.w * a[3][0];
        const float p1 = v.x * a[0][1] + v.y * a[1][1] + v.z * a[2][1] + v.w * a[3][1];
        const float p2 = v.x * a[0][2] + v.y * a[1][2] + v.z * a[2][2] + v.w * a[3][2];
        const float p3 = v.x * a[0][3] + v.y * a[1][3] + v.z * a[2][3] + v.w * a[3][3];
        float a01 = (lane & 1) ? p1 : p0;
        float b01 = (lane & 1) ? p0 : p1;
        a01 += __shfl_xor(b01, 1, 64);
        float a23 = (lane & 1) ? p3 : p2;
        float b23 = (lane & 1) ? p2 : p3;
        a23 += __shfl_xor(b23, 1, 64);
        float aa = (lane & 2) ? a23 : a01;
        float bb = (lane & 2) ? a01 : a23;
        aa += __shfl_xor(bb, 2, 64);
        aa += __shfl_xor(aa, 4, 64);
        aa += __shfl_xor(aa, 8, 64);
        aa += __shfl_xor(aa, 16, 64);
        red[k] = aa;
      }
#pragma unroll
      for (int k = 0; k < 8; ++k) {
        const float e0 = (idx[k] >= 0) ? __expf(red[k] + cl) : 0.f; // head myh
        const float e1 = __shfl_xor(e0, 1, 64);                     // head myh^1
        const float e2 = __shfl_xor(e0, 2, 64);                     // head myh^2
        const float e3 = __shfl_xor(e0, 3, 64);                     // head myh^3
        dsum[0] += e0; dsum[1] += e1; dsum[2] += e2; dsum[3] += e3;
        const float4 v = xv[k];
        xagg[0][0] += e0 * v.x; xagg[0][1] += e1 * v.x; xagg[0][2] += e2 * v.x; xagg[0][3] += e3 * v.x;
        xagg[1][0] += e0 * v.y; xagg[1][1] += e1 * v.y; xagg[1][2] += e2 * v.y; xagg[1][3] += e3 * v.y;
        xagg[2][0] += e0 * v.z; xagg[2][1] += e1 * v.z; xagg[2][2] += e2 * v.z; xagg[2][3] += e3 * v.z;
        xagg[3][0] += e0 * v.w; xagg[3][1] += e1 * v.w; xagg[3][2] += e2 * v.w; xagg[3][3] += e3 * v.w;
      }
#pragma unroll
      for (int k = 0; k < 8; ++k) idx[k] = idxn[k];
    }

#pragma unroll
    for (int dd = 0; dd < 4; ++dd)
#pragma unroll
      for (int h = 0; h < 4; ++h) xagg[dd][h] += __shfl_xor(xagg[dd][h], 32, 64);
#pragma unroll
    for (int h = 0; h < 4; ++h) dsum[h] += __shfl_xor(dsum[h], 32, 64);

    if (half == 0) {
      const bool m1 = (myh & 1) != 0;
      const bool m2 = (myh & 2) != 0;
      float outv[4][4]; // [abs head][dim]
#pragma unroll
      for (int dd = 0; dd < 4; ++dd) {
        const float b0 = m1 ? xagg[dd][1] : xagg[dd][0];
        const float b1 = m1 ? xagg[dd][0] : xagg[dd][1];
        const float b2 = m1 ? xagg[dd][3] : xagg[dd][2];
        const float b3 = m1 ? xagg[dd][2] : xagg[dd][3];
        outv[0][dd] = m2 ? b2 : b0;
        outv[1][dd] = m2 ? b3 : b1;
        outv[2][dd] = m2 ? b0 : b2;
        outv[3][dd] = m2 ? b1 : b3;
      }
#pragma unroll
      for (int h = 0; h < 4; ++h) {
        const float4 v = make_float4(outv[h][0], outv[h][1], outv[h][2], outv[h][3]);
        *reinterpret_cast<float4*>(Xagg + (size_t)r * 512 + h * 128 + d0) = v;
      }
      if (sl == 0) {
        *reinterpret_cast<float4*>(denom + (size_t)r * 4) =
            make_float4(dsum[0], dsum[1], dsum[2], dsum[3]);
      }
    }
  }
}

// ---------------- batched epilogue: attn -> O -> O+relu(O@Wo+bo) -> h = O2@Wg  (8 regions/block) --------
__global__ __launch_bounds__(256) void k_epilogue(
    const float* __restrict__ Xagg, const float* __restrict__ denom, const float* __restrict__ qvec,
    const float* __restrict__ Wv, const float* __restrict__ bv,
    const float* __restrict__ Wo, const float* __restrict__ bo,
    const float* __restrict__ Wg, float* __restrict__ hout, int R) {
  const int r0 = blockIdx.x * 8;
  const int tid = threadIdx.x;
  __shared__ float s_xa[8 * 512];
  __shared__ float s_den[8 * 4];
  __shared__ float s_O[8 * 128];
  __shared__ float s_O2[8 * 128];

  for (int t = tid; t < 8 * 512; t += 256) {
    int rl = t >> 9;
    s_xa[t] = (r0 + rl < R) ? Xagg[(size_t)r0 * 512 + t] : 0.f;
  }
  if (tid < 32) {
    int rl = tid >> 2;
    s_den[tid] = (r0 + rl < R) ? denom[r0 * 4 + tid] : 1.f;
  }
  __syncthreads();

  for (int o = tid; o < 1024; o += 256) {
    int rl = o >> 7, t = o & 127, h = t >> 5;
    float acc = 0.f;
    const float* xa = &s_xa[rl * 512 + h * 128];
    for (int j = 0; j < 128; j += 4) {
      float4 x4 = *reinterpret_cast<const float4*>(xa + j);
      acc += x4.x * Wv[j * 128 + t] + x4.y * Wv[(j + 1) * 128 + t]
           + x4.z * Wv[(j + 2) * 128 + t] + x4.w * Wv[(j + 3) * 128 + t];
    }
    float dn = s_den[rl * 4 + h];
    float attn = (acc + dn * bv[t]) / fmaxf(dn, 1e-9f);
    s_O[o] = qvec[t] + attn;
  }
  __syncthreads();

  for (int o = tid; o < 1024; o += 256) {
    int rl = o >> 7, t = o & 127;
    float acc = bo[t];
    const float* ov = &s_O[rl * 128];
    for (int j = 0; j < 128; j += 4) {
      float4 x4 = *reinterpret_cast<const float4*>(ov + j);
      acc += x4.x * Wo[j * 128 + t] + x4.y * Wo[(j + 1) * 128 + t]
           + x4.z * Wo[(j + 2) * 128 + t] + x4.w * Wo[(j + 3) * 128 + t];
    }
    s_O2[o] = s_O[o] + fmaxf(acc, 0.f);
  }
  __syncthreads();

  for (int o = tid; o < 1024; o += 256) {
    int rl = o >> 7, t = o & 127;
    float acc = 0.f;
    const float* ov = &s_O2[rl * 128];
    for (int j = 0; j < 128; j += 4) {
      float4 x4 = *reinterpret_cast<const float4*>(ov + j);
      acc += x4.x * Wg[j * 128 + t] + x4.y * Wg[(j + 1) * 128 + t]
           + x4.z * Wg[(j + 2) * 128 + t] + x4.w * Wg[(j + 3) * 128 + t];
    }
    if (r0 + rl < R) hout[(size_t)(r0 + rl) * 128 + t] = acc;
  }
}

// ---------------- fused GCN: self-loop + CSR edge gather + bias + PReLU (wave per region) ----------------
__global__ __launch_bounds__(256) void k_gcn(
    const int* __restrict__ estartb, const int* __restrict__ erow_s,
    const float* __restrict__ dinv, const float* __restrict__ hbuf,
    const float* __restrict__ bg, const float* __restrict__ pw,
    float* __restrict__ out, int R) {
  const int r = blockIdx.x * 4 + (threadIdx.x >> 6);
  if (r >= R) return;
  const int lane = threadIdx.x & 63;
  const int d0 = lane * 2;
  const float dr = dinv[r];
  const float2 hc = *reinterpret_cast<const float2*>(hbuf + (size_t)r * 128 + d0);
  float accx = dr * dr * hc.x;
  float accy = dr * dr * hc.y;
  const int e0 = estartb[r], e1 = estartb[r + 1];
  for (int e = e0; e < e1; ++e) {
    const int rr = erow_s[e];
    const float w = dinv[rr] * dr;
    const float2 hv = *reinterpret_cast<const float2*>(hbuf + (size_t)rr * 128 + d0);
    accx += w * hv.x;
    accy += w * hv.y;
  }
  const float2 b = *reinterpret_cast<const float2*>(bg + d0);
  const float2 pv = *reinterpret_cast<const float2*>(pw + d0);
  const float t0 = accx + b.x;
  const float t1 = accy + b.y;
  out[(size_t)r * 128 + d0]     = (t0 >= 0.f) ? t0 : pv.x * t0;
  out[(size_t)r * 128 + d0 + 1] = (t1 >= 0.f) ? t1 : pv.y * t1;
}

// ---------------- host ----------------
extern "C" void kernel_launch(void* const* d_in, const int* in_sizes, int n_in,
                              void* d_out, int out_size, void* d_ws, size_t ws_size,
                              hipStream_t stream) {
  const float* x   = (const float*)d_in[0];
  const int*   zone = (const int*)d_in[1];
  const int*   eidx = (const int*)d_in[2];
  const float* S   = (const float*)d_in[4];
  const float* Wq  = (const float*)d_in[5];
  const float* bq  = (const float*)d_in[6];
  const float* Wk  = (const float*)d_in[7];
  const float* bk  = (const float*)d_in[8];
  const float* Wv  = (const float*)d_in[9];
  const float* bv  = (const float*)d_in[10];
  const float* Wo  = (const float*)d_in[11];
  const float* bo  = (const float*)d_in[12];
  const float* Wg  = (const float*)d_in[13];
  const float* bg  = (const float*)d_in[14];
  const float* pw  = (const float*)d_in[15];
  float* out = (float*)d_out;

  const int N = in_sizes[0] / 128;
  const int E = in_sizes[2] / 2;
  const int R = out_size / 128;
  const int* erow = eidx;
  const int* ecol = eidx + E;

  char* wsb = (char*)d_ws;
  size_t off = 0;
  auto alloc = [&](size_t bytes) -> void* {
    void* p = wsb + off;
    off = (off + bytes + 255) & ~(size_t)255;
    return p;
  };
  // zeroed int block: counts | ecounts
  int* izero  = (int*)alloc((size_t)2 * R * 4 + 16);
  int* counts = izero;
  int* ecounts= izero + R;

  float* qvec  = (float*)alloc(128 * 4);
  float* A     = (float*)alloc(512 * 4);
  float* cvec  = (float*)alloc(4 * 4);
  int*   startb = (int*)alloc((size_t)(R + 1) * 4);
  int*   estartb= (int*)alloc((size_t)(R + 1) * 4);
  float* dinv  = (float*)alloc((size_t)R * 4);
  int*   erow_s= (int*)alloc((size_t)E * 4);
  int*   epos  = (int*)alloc((size_t)E * 4);
  int*   perm  = (int*)alloc((size_t)N * 4);
  int*   pos   = (int*)alloc((size_t)N * 4);
  float* Xagg  = (float*)alloc((size_t)R * 512 * 4);
  float* denom = (float*)alloc((size_t)R * 4 * 4);
  float* hbuf  = (float*)alloc((size_t)R * 128 * 4);

  const int n4 = (2 * R + 3) / 4;
  k_zero<<<(n4 + 255) / 256, 256, 0, stream>>>(izero, n4);
  k_hist2<<<(N + E + 255) / 256, 256, 0, stream>>>(zone, N, ecol, E, counts, ecounts, pos, epos);
  k_scan3<<<3, 256, 0, stream>>>(counts, ecounts, R, startb, estartb, dinv,
                                 S, Wq, bq, Wk, bk, qvec, A, cvec);
  k_scatter2<<<(N + E + 255) / 256, 256, 0, stream>>>(zone, N, pos, erow, ecol, E, epos,
                                                      startb, perm, estartb, erow_s);
  k_fused<<<1024, 256, 0, stream>>>(x, perm, startb, A, cvec, Xagg, denom, R);
  k_epilogue<<<(R + 7) / 8, 256, 0, stream>>>(Xagg, denom, qvec, Wv, bv, Wo, bo, Wg, hbuf, R);
  k_gcn<<<(R + 3) / 4, 256, 0, stream>>>(estartb, erow_s, dinv, hbuf, bg, pw, out, R);
}